// Round 10
// baseline (188.361 us; speedup 1.0000x reference)
//
#include <hip/hip_runtime.h>

#define IN_CH 128
#define HID 64
#define NEG 0.2f

typedef short bf16x8 __attribute__((ext_vector_type(8)));
typedef float f32x4  __attribute__((ext_vector_type(4)));

__device__ __forceinline__ unsigned short f2bf(float f) {
    unsigned u = __float_as_uint(f);
    u += 0x7fffu + ((u >> 16) & 1u);   // RNE
    return (unsigned short)(u >> 16);
}
__device__ __forceinline__ float bf2f(unsigned short h) {
    return __uint_as_float((unsigned)h << 16);
}

// ------- K1: MFMA projections + fused quarter-bucket edge partition ---------
// (unchanged from R9)
__global__ __launch_bounds__(512, 4) void proj_part(
    const float* __restrict__ x, const float* __restrict__ W_l,
    const float* __restrict__ W_r,
    unsigned short* __restrict__ xlb, float* __restrict__ xr,
    const int* __restrict__ src, const int* __restrict__ dst,
    int* __restrict__ gcursor, unsigned* __restrict__ pairs,
    int nN, int E)
{
    __shared__ unsigned short A_hi[64 * 136];   // 17.4 KB
    __shared__ unsigned short A_lo[64 * 136];   // 17.4 KB
    int tid = threadIdx.x;
    int nb = blockIdx.x * 64;
    int lane = tid & 63;
    int wid = __builtin_amdgcn_readfirstlane(tid >> 6);
    int mat = wid >> 2;
    int ct  = (wid & 3) * 16;
    int n = lane & 15, quad = lane >> 4;

    const float* __restrict__ W = mat ? W_r : W_l;
    bf16x8 Bh[4], Bl[4];
    #pragma unroll
    for (int s = 0; s < 4; ++s) {
        const float* wr = W + (size_t)(ct + n) * IN_CH + s * 32 + quad * 8;
        float4 w0 = *(const float4*)(wr);
        float4 w1 = *(const float4*)(wr + 4);
        float wf[8] = {w0.x, w0.y, w0.z, w0.w, w1.x, w1.y, w1.z, w1.w};
        #pragma unroll
        for (int j = 0; j < 8; ++j) {
            unsigned short h = f2bf(wf[j]);
            Bh[s][j] = (short)h;
            Bl[s][j] = (short)f2bf(wf[j] - bf2f(h));
        }
    }

    #pragma unroll
    for (int it = 0; it < 2; ++it) {
        int gi = it * 512 + tid;
        int row = gi >> 4, c8 = gi & 15;
        int node = nb + row;
        uint4 hi = make_uint4(0, 0, 0, 0), lo = make_uint4(0, 0, 0, 0);
        if (node < nN) {
            const float* xp = x + (size_t)node * IN_CH + c8 * 8;
            float4 f0 = *(const float4*)(xp);
            float4 f1 = *(const float4*)(xp + 4);
            float xf[8] = {f0.x, f0.y, f0.z, f0.w, f1.x, f1.y, f1.z, f1.w};
            unsigned hh[8], ll[8];
            #pragma unroll
            for (int j = 0; j < 8; ++j) {
                unsigned short h = f2bf(xf[j]);
                hh[j] = h;
                ll[j] = f2bf(xf[j] - bf2f(h));
            }
            hi = make_uint4(hh[0] | (hh[1] << 16), hh[2] | (hh[3] << 16),
                            hh[4] | (hh[5] << 16), hh[6] | (hh[7] << 16));
            lo = make_uint4(ll[0] | (ll[1] << 16), ll[2] | (ll[3] << 16),
                            ll[4] | (ll[5] << 16), ll[6] | (ll[7] << 16));
        }
        *(uint4*)(&A_hi[row * 136 + c8 * 8]) = hi;
        *(uint4*)(&A_lo[row * 136 + c8 * 8]) = lo;
    }
    __syncthreads();

    #pragma unroll
    for (int mt = 0; mt < 4; ++mt) {
        f32x4 d = {0.f, 0.f, 0.f, 0.f};
        int arow = (mt * 16 + n) * 136 + quad * 8;
        #pragma unroll
        for (int s = 0; s < 4; ++s) {
            bf16x8 ah = *(const bf16x8*)(&A_hi[arow + s * 32]);
            bf16x8 al = *(const bf16x8*)(&A_lo[arow + s * 32]);
            d = __builtin_amdgcn_mfma_f32_16x16x32_bf16(ah, Bh[s], d, 0, 0, 0);
            d = __builtin_amdgcn_mfma_f32_16x16x32_bf16(ah, Bl[s], d, 0, 0, 0);
            d = __builtin_amdgcn_mfma_f32_16x16x32_bf16(al, Bh[s], d, 0, 0, 0);
        }
        #pragma unroll
        for (int r = 0; r < 4; ++r) {
            int node = nb + mt * 16 + quad * 4 + r;
            if (node < nN) {
                if (mat)
                    xr[(size_t)node * HID + ct + n] = d[r];
                else
                    xlb[(size_t)node * HID + ct + n] = f2bf(d[r]);
            }
        }
    }

    // ------- Phase B: rank-stash single-pass append (4096 quarter-buckets) --
    __syncthreads();
    int* lh = (int*)A_hi;          // lhist[4096] (atomic returns rank)
    int* lb = (int*)A_lo;          // lbase[4096]
    for (int i = tid; i < 4096; i += 512) lh[i] = 0;
    __syncthreads();

    int G = (int)gridDim.x;
    int C = ((E + G - 1) / G + 3) & ~3;          // chunk, multiple of 4 (~1536)
    int lo = blockIdx.x * C;
    int hi = lo + C; if (hi > E) hi = E;

    int i0 = lo + tid * 4;
    unsigned pay[4];
    int bk[4], rk[4];
    int ne = 0;
    if (i0 + 3 < hi) {
        int4 s4 = *(const int4*)(src + i0);
        int4 d4 = *(const int4*)(dst + i0);
        bk[0] = d4.x >> 4; pay[0] = (unsigned)s4.x | (((unsigned)d4.x & 15u) << 16);
        bk[1] = d4.y >> 4; pay[1] = (unsigned)s4.y | (((unsigned)d4.y & 15u) << 16);
        bk[2] = d4.z >> 4; pay[2] = (unsigned)s4.z | (((unsigned)d4.z & 15u) << 16);
        bk[3] = d4.w >> 4; pay[3] = (unsigned)s4.w | (((unsigned)d4.w & 15u) << 16);
        ne = 4;
        #pragma unroll
        for (int q = 0; q < 4; ++q) rk[q] = atomicAdd(&lh[bk[q]], 1);
    } else {
        for (int j = i0; j < hi; ++j) {
            int s = src[j], d = dst[j];
            bk[ne] = d >> 4;
            pay[ne] = (unsigned)s | (((unsigned)d & 15u) << 16);
            rk[ne] = atomicAdd(&lh[bk[ne]], 1);
            ++ne;
        }
    }
    __syncthreads();
    for (int i = tid; i < 4096; i += 512) {
        int c = lh[i];
        lb[i] = c ? atomicAdd(&gcursor[i], c) : 0;
    }
    __syncthreads();
    for (int q = 0; q < ne; ++q) {
        int p = lb[bk[q]] + rk[q];
        if (p < 512) pairs[(bk[q] << 9) + p] = pay[q];
    }
}

// ------- K2: quarter-bucket sort + wave attention + MFMA epilogue -----------
// 128-thread blocks (2 waves): wave-slot cap becomes 16 blocks/CU, so the
// whole ~3125-block grid is co-resident (~24 waves/CU vs 18 at 256-thread).
// Inner edge loop identical to R9. Each wave: 8 nodes; epilogue: 2 col-tiles.
__global__ __launch_bounds__(128, 8) void gat_sorted(
    const unsigned short* __restrict__ xlb, const float* __restrict__ xr,
    const unsigned* __restrict__ pairs, const int* __restrict__ bcnt,
    const float* __restrict__ att, const float* __restrict__ bias_conv,
    const float* __restrict__ W_lin, const float* __restrict__ b_lin,
    float* __restrict__ out, int nN)
{
    __shared__ unsigned short sorted[512];    // 1 KB
    __shared__ unsigned short Hhi[16 * 72];   // 2.25 KB
    __shared__ unsigned short Hlo[16 * 72];   // 2.25 KB
    __shared__ int cnt[16];
    __shared__ int rs[17];
    int tid = threadIdx.x;
    if (tid < 16) cnt[tid] = 0;
    __syncthreads();

    int blk = blockIdx.x;          // quarter-bucket of 16 dst nodes
    int M = bcnt[blk];
    if (M > 512) M = 512;
    const unsigned* __restrict__ pb = pairs + ((size_t)blk << 9);

    // coalesced load; rank-stash (atomic returns within-bucket rank)
    unsigned ew[4];
    int dl[4], rk[4];
    int ne = 0;
    for (int i = tid; i < M; i += 128) {
        unsigned w = pb[i];
        ew[ne] = w;
        dl[ne] = (w >> 16) & 15;
        rk[ne] = atomicAdd(&cnt[dl[ne]], 1);
        ++ne;
    }
    __syncthreads();
    if (tid < 16) {
        int c = cnt[tid];
        int s = c;
        #pragma unroll
        for (int d = 1; d < 16; d <<= 1) {
            int t = __shfl_up(s, d, 64);
            if (tid >= d) s += t;
        }
        rs[tid] = s - c;
        if (tid == 15) rs[16] = s;
    }
    __syncthreads();
    for (int q = 0; q < ne; ++q)
        sorted[rs[dl[q]] + rk[q]] = (unsigned short)(ew[q] & 0xFFFFu);
    __syncthreads();

    // per-node processing: 2 waves x 8 nodes each
    int lane = tid & 63, wv = tid >> 6;
    int g = lane >> 4, gl = lane & 15;
    const float4 att4 = *(const float4*)(att + gl * 4);
    // att . LeakyReLU(t) == sum c1*att_c*t + c2*att_c*|t|
    const float c1 = 0.5f * (1.f + NEG), c2 = 0.5f * (1.f - NEG);
    float4 a1 = make_float4(c1 * att4.x, c1 * att4.y, c1 * att4.z, c1 * att4.w);
    float4 a2 = make_float4(c2 * att4.x, c2 * att4.y, c2 * att4.z, c2 * att4.w);
    int nb = blk * 16;
    for (int t = 0; t < 8; ++t) {
        int nl = wv * 8 + t;
        int node = nb + nl;
        if (node >= nN) break;
        const float4 xr4 = *(const float4*)(xr + (size_t)node * HID + gl * 4);
        float4 acc = make_float4(0.f, 0.f, 0.f, 0.f);
        float denom = 0.f;
        // self loop: group 0 only
        if (g == 0) {
            ushort4 us = *(const ushort4*)(xlb + (size_t)node * HID + gl * 4);
            float xsx = bf2f(us.x), xsy = bf2f(us.y), xsz = bf2f(us.z), xsw = bf2f(us.w);
            float tx = xsx + xr4.x, ty = xsy + xr4.y;
            float tz = xsz + xr4.z, tw = xsw + xr4.w;
            float r = a1.x * tx;
            r = fmaf(a2.x, fabsf(tx), r);
            r = fmaf(a1.y, ty, r); r = fmaf(a2.y, fabsf(ty), r);
            r = fmaf(a1.z, tz, r); r = fmaf(a2.z, fabsf(tz), r);
            r = fmaf(a1.w, tw, r); r = fmaf(a2.w, fabsf(tw), r);
            r += __shfl_xor(r, 1, 64);
            r += __shfl_xor(r, 2, 64);
            r += __shfl_xor(r, 4, 64);
            r += __shfl_xor(r, 8, 64);
            float ev = __expf(r);
            denom = ev;
            acc.x = ev * xsx; acc.y = ev * xsy;
            acc.z = ev * xsz; acc.w = ev * xsw;
        }
        int s0 = rs[nl], s1 = rs[nl + 1];
        int last = s1 - 1;
        for (int base = s0; base < s1; base += 16) {
            int kb = base + g * 4;
            int k0 = (kb     <= last) ? kb     : last;
            int k1 = (kb + 1 <= last) ? kb + 1 : last;
            int k2 = (kb + 2 <= last) ? kb + 2 : last;
            int k3 = (kb + 3 <= last) ? kb + 3 : last;
            int j0 = sorted[k0], j1 = sorted[k1], j2 = sorted[k2], j3 = sorted[k3];
            ushort4 ua = *(const ushort4*)(xlb + (size_t)j0 * HID + gl * 4);
            ushort4 ub = *(const ushort4*)(xlb + (size_t)j1 * HID + gl * 4);
            ushort4 uc = *(const ushort4*)(xlb + (size_t)j2 * HID + gl * 4);
            ushort4 ud = *(const ushort4*)(xlb + (size_t)j3 * HID + gl * 4);
            float xax = bf2f(ua.x), xay = bf2f(ua.y), xaz = bf2f(ua.z), xaw = bf2f(ua.w);
            float xbx = bf2f(ub.x), xby = bf2f(ub.y), xbz = bf2f(ub.z), xbw = bf2f(ub.w);
            float xcx = bf2f(uc.x), xcy = bf2f(uc.y), xcz = bf2f(uc.z), xcw = bf2f(uc.w);
            float xdx = bf2f(ud.x), xdy = bf2f(ud.y), xdz = bf2f(ud.z), xdw = bf2f(ud.w);

            float t0, t1, t2, t3, ra, rb, rc, rd;
            t0 = xax + xr4.x; t1 = xay + xr4.y; t2 = xaz + xr4.z; t3 = xaw + xr4.w;
            ra = a1.x * t0;        ra = fmaf(a2.x, fabsf(t0), ra);
            ra = fmaf(a1.y, t1, ra); ra = fmaf(a2.y, fabsf(t1), ra);
            ra = fmaf(a1.z, t2, ra); ra = fmaf(a2.z, fabsf(t2), ra);
            ra = fmaf(a1.w, t3, ra); ra = fmaf(a2.w, fabsf(t3), ra);
            t0 = xbx + xr4.x; t1 = xby + xr4.y; t2 = xbz + xr4.z; t3 = xbw + xr4.w;
            rb = a1.x * t0;        rb = fmaf(a2.x, fabsf(t0), rb);
            rb = fmaf(a1.y, t1, rb); rb = fmaf(a2.y, fabsf(t1), rb);
            rb = fmaf(a1.z, t2, rb); rb = fmaf(a2.z, fabsf(t2), rb);
            rb = fmaf(a1.w, t3, rb); rb = fmaf(a2.w, fabsf(t3), rb);
            t0 = xcx + xr4.x; t1 = xcy + xr4.y; t2 = xcz + xr4.z; t3 = xcw + xr4.w;
            rc = a1.x * t0;        rc = fmaf(a2.x, fabsf(t0), rc);
            rc = fmaf(a1.y, t1, rc); rc = fmaf(a2.y, fabsf(t1), rc);
            rc = fmaf(a1.z, t2, rc); rc = fmaf(a2.z, fabsf(t2), rc);
            rc = fmaf(a1.w, t3, rc); rc = fmaf(a2.w, fabsf(t3), rc);
            t0 = xdx + xr4.x; t1 = xdy + xr4.y; t2 = xdz + xr4.z; t3 = xdw + xr4.w;
            rd = a1.x * t0;        rd = fmaf(a2.x, fabsf(t0), rd);
            rd = fmaf(a1.y, t1, rd); rd = fmaf(a2.y, fabsf(t1), rd);
            rd = fmaf(a1.z, t2, rd); rd = fmaf(a2.z, fabsf(t2), rd);
            rd = fmaf(a1.w, t3, rd); rd = fmaf(a2.w, fabsf(t3), rd);

            ra += __shfl_xor(ra, 1, 64); rb += __shfl_xor(rb, 1, 64);
            rc += __shfl_xor(rc, 1, 64); rd += __shfl_xor(rd, 1, 64);
            ra += __shfl_xor(ra, 2, 64); rb += __shfl_xor(rb, 2, 64);
            rc += __shfl_xor(rc, 2, 64); rd += __shfl_xor(rd, 2, 64);
            ra += __shfl_xor(ra, 4, 64); rb += __shfl_xor(rb, 4, 64);
            rc += __shfl_xor(rc, 4, 64); rd += __shfl_xor(rd, 4, 64);
            ra += __shfl_xor(ra, 8, 64); rb += __shfl_xor(rb, 8, 64);
            rc += __shfl_xor(rc, 8, 64); rd += __shfl_xor(rd, 8, 64);

            float ea = (kb     < s1) ? __expf(ra) : 0.f;
            float eb = (kb + 1 < s1) ? __expf(rb) : 0.f;
            float ec = (kb + 2 < s1) ? __expf(rc) : 0.f;
            float ed = (kb + 3 < s1) ? __expf(rd) : 0.f;
            denom += (ea + eb) + (ec + ed);
            acc.x = fmaf(ea, xax, acc.x); acc.x = fmaf(eb, xbx, acc.x);
            acc.x = fmaf(ec, xcx, acc.x); acc.x = fmaf(ed, xdx, acc.x);
            acc.y = fmaf(ea, xay, acc.y); acc.y = fmaf(eb, xby, acc.y);
            acc.y = fmaf(ec, xcy, acc.y); acc.y = fmaf(ed, xdy, acc.y);
            acc.z = fmaf(ea, xaz, acc.z); acc.z = fmaf(eb, xbz, acc.z);
            acc.z = fmaf(ec, xcz, acc.z); acc.z = fmaf(ed, xdz, acc.z);
            acc.w = fmaf(ea, xaw, acc.w); acc.w = fmaf(eb, xbw, acc.w);
            acc.w = fmaf(ec, xcw, acc.w); acc.w = fmaf(ed, xdw, acc.w);
        }
        denom += __shfl_xor(denom, 16, 64);
        denom += __shfl_xor(denom, 32, 64);
        acc.x += __shfl_xor(acc.x, 16, 64); acc.x += __shfl_xor(acc.x, 32, 64);
        acc.y += __shfl_xor(acc.y, 16, 64); acc.y += __shfl_xor(acc.y, 32, 64);
        acc.z += __shfl_xor(acc.z, 16, 64); acc.z += __shfl_xor(acc.z, 32, 64);
        acc.w += __shfl_xor(acc.w, 16, 64); acc.w += __shfl_xor(acc.w, 32, 64);
        float inv = 1.f / (denom + 1e-16f);
        float4 b4 = *(const float4*)(bias_conv + gl * 4);
        float hx = fmaf(acc.x, inv, b4.x);
        float hy = fmaf(acc.y, inv, b4.y);
        float hz = fmaf(acc.z, inv, b4.z);
        float hw = fmaf(acc.w, inv, b4.w);
        hx = (hx > 0.f) ? hx : (__expf(hx) - 1.f);
        hy = (hy > 0.f) ? hy : (__expf(hy) - 1.f);
        hz = (hz > 0.f) ? hz : (__expf(hz) - 1.f);
        hw = (hw > 0.f) ? hw : (__expf(hw) - 1.f);
        if (g == 0) {
            unsigned short hix = f2bf(hx), hiy = f2bf(hy),
                           hiz = f2bf(hz), hiw = f2bf(hw);
            ushort4 vhi = make_ushort4(hix, hiy, hiz, hiw);
            ushort4 vlo = make_ushort4(f2bf(hx - bf2f(hix)), f2bf(hy - bf2f(hiy)),
                                       f2bf(hz - bf2f(hiz)), f2bf(hw - bf2f(hiw)));
            *(ushort4*)(&Hhi[nl * 72 + gl * 4]) = vhi;
            *(ushort4*)(&Hlo[nl * 72 + gl * 4]) = vlo;
        }
    }
    __syncthreads();

    // ---- block-level epilogue GEMM: out[16x64] = H[16x64] @ W_lin^T --------
    // 2 waves x 2 column-tiles each (cols = wv*32 + cc*16 + gl)
    float blin;
    #pragma unroll
    for (int cc = 0; cc < 2; ++cc) {
        int colb = wv * 32 + cc * 16;
        bf16x8 Wh[2], Wl[2];
        #pragma unroll
        for (int s = 0; s < 2; ++s) {
            const float* wr = W_lin + (size_t)(colb + gl) * HID + s * 32 + g * 8;
            float4 w0 = *(const float4*)(wr);
            float4 w1 = *(const float4*)(wr + 4);
            float wf[8] = {w0.x, w0.y, w0.z, w0.w, w1.x, w1.y, w1.z, w1.w};
            #pragma unroll
            for (int j = 0; j < 8; ++j) {
                unsigned short h = f2bf(wf[j]);
                Wh[s][j] = (short)h;
                Wl[s][j] = (short)f2bf(wf[j] - bf2f(h));
            }
        }
        blin = b_lin[colb + gl];
        f32x4 d = {0.f, 0.f, 0.f, 0.f};
        int arow = gl * 72 + g * 8;
        #pragma unroll
        for (int s = 0; s < 2; ++s) {
            bf16x8 ah = *(const bf16x8*)(&Hhi[arow + s * 32]);
            bf16x8 al = *(const bf16x8*)(&Hlo[arow + s * 32]);
            d = __builtin_amdgcn_mfma_f32_16x16x32_bf16(ah, Wh[s], d, 0, 0, 0);
            d = __builtin_amdgcn_mfma_f32_16x16x32_bf16(ah, Wl[s], d, 0, 0, 0);
            d = __builtin_amdgcn_mfma_f32_16x16x32_bf16(al, Wh[s], d, 0, 0, 0);
        }
        #pragma unroll
        for (int r = 0; r < 4; ++r) {
            int node = nb + g * 4 + r;
            if (node < nN)
                out[(size_t)node * HID + colb + gl] = d[r] + blin;
        }
    }
}

extern "C" void kernel_launch(void* const* d_in, const int* in_sizes, int n_in,
                              void* d_out, int out_size, void* d_ws, size_t ws_size,
                              hipStream_t stream) {
    const float* x      = (const float*)d_in[0];
    const int*   ei     = (const int*)d_in[1];
    // d_in[2] = edge_weight: unused by the reference
    const float* W_l    = (const float*)d_in[3];
    const float* W_r    = (const float*)d_in[4];
    const float* att    = (const float*)d_in[5];
    const float* bias_c = (const float*)d_in[6];
    const float* W_lin  = (const float*)d_in[7];
    const float* b_lin  = (const float*)d_in[8];
    float* out = (float*)d_out;

    int N = in_sizes[0] / IN_CH;
    int E = in_sizes[2];
    const int* srcp = ei;
    const int* dstp = ei + E;
    int NB = (N + 63) / 64;   // proj blocks
    int NQ = (N + 15) / 16;   // quarter-buckets (<= 4096)

    char* ws = (char*)d_ws;
    float* xr = (float*)ws;                                         // N*64 f32
    unsigned short* xlb = (unsigned short*)(xr + (size_t)N * HID);  // N*64 bf16
    int* gcursor = (int*)(xlb + (size_t)N * HID);                   // 4096
    unsigned* pairs = (unsigned*)(gcursor + 4096);                  // NQ*512

    hipMemsetAsync(gcursor, 0, 4096 * sizeof(int), stream);
    proj_part<<<NB, 512, 0, stream>>>(x, W_l, W_r, xlb, xr, srcp, dstp,
                                      gcursor, pairs, N, E);
    gat_sorted<<<NQ, 128, 0, stream>>>(xlb, xr, pairs, gcursor,
                                       att, bias_c, W_lin, b_lin, out, N);
}

// Round 11
// 173.852 us; speedup vs baseline: 1.0835x; 1.0835x over previous
//
#include <hip/hip_runtime.h>

#define IN_CH 128
#define HID 64
#define NEG 0.2f

typedef short bf16x8 __attribute__((ext_vector_type(8)));
typedef float f32x4  __attribute__((ext_vector_type(4)));

__device__ __forceinline__ unsigned short f2bf(float f) {
    unsigned u = __float_as_uint(f);
    u += 0x7fffu + ((u >> 16) & 1u);   // RNE
    return (unsigned short)(u >> 16);
}
__device__ __forceinline__ float bf2f(unsigned short h) {
    return __uint_as_float((unsigned)h << 16);
}

// ------- K1: MFMA projections + fused edge-append partition -----------------
// EXACT R8 form (best-measured proj): rank-stash single pass into 1024
// bucket regions (64 dst nodes each, 2048-slot capacity). ~618K reserve
// atomics total (vs 1.0M at 4096-way -- R9's +8us regression root cause).
__global__ __launch_bounds__(512, 4) void proj_part(
    const float* __restrict__ x, const float* __restrict__ W_l,
    const float* __restrict__ W_r,
    unsigned short* __restrict__ xlb, float* __restrict__ xr,
    const int* __restrict__ src, const int* __restrict__ dst,
    int* __restrict__ gcursor, unsigned* __restrict__ pairs,
    int nN, int E)
{
    __shared__ unsigned short A_hi[64 * 136];   // 17.4 KB
    __shared__ unsigned short A_lo[64 * 136];   // 17.4 KB
    int tid = threadIdx.x;
    int nb = blockIdx.x * 64;
    int lane = tid & 63;
    int wid = __builtin_amdgcn_readfirstlane(tid >> 6);
    int mat = wid >> 2;
    int ct  = (wid & 3) * 16;
    int n = lane & 15, quad = lane >> 4;

    const float* __restrict__ W = mat ? W_r : W_l;
    bf16x8 Bh[4], Bl[4];
    #pragma unroll
    for (int s = 0; s < 4; ++s) {
        const float* wr = W + (size_t)(ct + n) * IN_CH + s * 32 + quad * 8;
        float4 w0 = *(const float4*)(wr);
        float4 w1 = *(const float4*)(wr + 4);
        float wf[8] = {w0.x, w0.y, w0.z, w0.w, w1.x, w1.y, w1.z, w1.w};
        #pragma unroll
        for (int j = 0; j < 8; ++j) {
            unsigned short h = f2bf(wf[j]);
            Bh[s][j] = (short)h;
            Bl[s][j] = (short)f2bf(wf[j] - bf2f(h));
        }
    }

    #pragma unroll
    for (int it = 0; it < 2; ++it) {
        int gi = it * 512 + tid;
        int row = gi >> 4, c8 = gi & 15;
        int node = nb + row;
        uint4 hi = make_uint4(0, 0, 0, 0), lo = make_uint4(0, 0, 0, 0);
        if (node < nN) {
            const float* xp = x + (size_t)node * IN_CH + c8 * 8;
            float4 f0 = *(const float4*)(xp);
            float4 f1 = *(const float4*)(xp + 4);
            float xf[8] = {f0.x, f0.y, f0.z, f0.w, f1.x, f1.y, f1.z, f1.w};
            unsigned hh[8], ll[8];
            #pragma unroll
            for (int j = 0; j < 8; ++j) {
                unsigned short h = f2bf(xf[j]);
                hh[j] = h;
                ll[j] = f2bf(xf[j] - bf2f(h));
            }
            hi = make_uint4(hh[0] | (hh[1] << 16), hh[2] | (hh[3] << 16),
                            hh[4] | (hh[5] << 16), hh[6] | (hh[7] << 16));
            lo = make_uint4(ll[0] | (ll[1] << 16), ll[2] | (ll[3] << 16),
                            ll[4] | (ll[5] << 16), ll[6] | (ll[7] << 16));
        }
        *(uint4*)(&A_hi[row * 136 + c8 * 8]) = hi;
        *(uint4*)(&A_lo[row * 136 + c8 * 8]) = lo;
    }
    __syncthreads();

    #pragma unroll
    for (int mt = 0; mt < 4; ++mt) {
        f32x4 d = {0.f, 0.f, 0.f, 0.f};
        int arow = (mt * 16 + n) * 136 + quad * 8;
        #pragma unroll
        for (int s = 0; s < 4; ++s) {
            bf16x8 ah = *(const bf16x8*)(&A_hi[arow + s * 32]);
            bf16x8 al = *(const bf16x8*)(&A_lo[arow + s * 32]);
            d = __builtin_amdgcn_mfma_f32_16x16x32_bf16(ah, Bh[s], d, 0, 0, 0);
            d = __builtin_amdgcn_mfma_f32_16x16x32_bf16(ah, Bl[s], d, 0, 0, 0);
            d = __builtin_amdgcn_mfma_f32_16x16x32_bf16(al, Bh[s], d, 0, 0, 0);
        }
        #pragma unroll
        for (int r = 0; r < 4; ++r) {
            int node = nb + mt * 16 + quad * 4 + r;
            if (node < nN) {
                if (mat)
                    xr[(size_t)node * HID + ct + n] = d[r];
                else
                    xlb[(size_t)node * HID + ct + n] = f2bf(d[r]);
            }
        }
    }

    // ---------------- Phase B: rank-stash single-pass append ----------------
    __syncthreads();
    int* lh = (int*)A_hi;          // lhist[1024] (counts; atomic returns rank)
    int* lb = lh + 1024;           // lbase[1024]
    for (int i = tid; i < 1024; i += 512) lh[i] = 0;
    __syncthreads();

    int G = (int)gridDim.x;
    int C = ((E + G - 1) / G + 3) & ~3;          // chunk, multiple of 4 (~1536)
    int lo = blockIdx.x * C;
    int hi = lo + C; if (hi > E) hi = E;

    // each thread owns up to 4 consecutive edges at i0 (C <= 2048 = 512*4)
    int i0 = lo + tid * 4;
    unsigned pay[4];
    int bk[4], rk[4];
    int ne = 0;
    if (i0 + 3 < hi) {
        int4 s4 = *(const int4*)(src + i0);
        int4 d4 = *(const int4*)(dst + i0);
        bk[0] = d4.x >> 6; pay[0] = (unsigned)s4.x | (((unsigned)d4.x & 63u) << 16);
        bk[1] = d4.y >> 6; pay[1] = (unsigned)s4.y | (((unsigned)d4.y & 63u) << 16);
        bk[2] = d4.z >> 6; pay[2] = (unsigned)s4.z | (((unsigned)d4.z & 63u) << 16);
        bk[3] = d4.w >> 6; pay[3] = (unsigned)s4.w | (((unsigned)d4.w & 63u) << 16);
        ne = 4;
        #pragma unroll
        for (int q = 0; q < 4; ++q) rk[q] = atomicAdd(&lh[bk[q]], 1);
    } else {
        for (int j = i0; j < hi; ++j) {
            int s = src[j], d = dst[j];
            bk[ne] = d >> 6;
            pay[ne] = (unsigned)s | (((unsigned)d & 63u) << 16);
            rk[ne] = atomicAdd(&lh[bk[ne]], 1);
            ++ne;
        }
    }
    __syncthreads();
    for (int i = tid; i < 1024; i += 512) {
        int c = lh[i];
        lb[i] = c ? atomicAdd(&gcursor[i], c) : 0;
    }
    __syncthreads();
    for (int q = 0; q < ne; ++q) {
        int p = lb[bk[q]] + rk[q];
        if (p < 2048) pairs[(bk[q] << 11) + p] = pay[q];
    }
}

// ------- K2: quarter-block attention on 1024-bucket partition ---------------
// Block = one 16-node QUARTER of a 64-node bucket (grid = NB*4 ~ 3128).
// Scans the bucket's pairs region, keeps only its quarter ((w>>20)&3 == qq),
// single-pass rank-stash sort, then R9's 4-wave x 4-node loop + 16x64 MFMA
// epilogue. Decouples partition granularity (coarse, cheap atomics) from
// consumption granularity (fine, high occupancy).
__global__ __launch_bounds__(256, 8) void gat_sorted(
    const unsigned short* __restrict__ xlb, const float* __restrict__ xr,
    const unsigned* __restrict__ pairs, const int* __restrict__ bcnt,
    const float* __restrict__ att, const float* __restrict__ bias_conv,
    const float* __restrict__ W_lin, const float* __restrict__ b_lin,
    float* __restrict__ out, int nN)
{
    __shared__ unsigned short sorted[512];    // 1 KB (quarter mean 384, +6.4σ)
    __shared__ unsigned short Hhi[16 * 72];   // 2.25 KB
    __shared__ unsigned short Hlo[16 * 72];   // 2.25 KB
    __shared__ int cnt[16];
    __shared__ int rs[17];
    int tid = threadIdx.x;
    if (tid < 16) cnt[tid] = 0;
    __syncthreads();

    int blk = blockIdx.x;
    int b  = blk >> 2;             // 64-node bucket
    int qq = blk & 3;              // which 16-node quarter we own
    int M = bcnt[b];
    if (M > 2048) M = 2048;
    const unsigned* __restrict__ pb = pairs + ((size_t)b << 11);

    // coalesced scan of bucket pairs; keep our quarter; rank-stash
    unsigned ew[8];
    int ml[8];                     // (rk<<4) | dl
    int ne = 0;
    for (int i = tid; i < M; i += 256) {
        unsigned w = pb[i];
        if (((w >> 20) & 3u) == (unsigned)qq) {
            int dl = (w >> 16) & 15;
            int r = atomicAdd(&cnt[dl], 1);
            ew[ne] = w;
            ml[ne] = (r << 4) | dl;
            ++ne;
        }
    }
    __syncthreads();
    if (tid < 16) {
        int c = cnt[tid];
        int s = c;
        #pragma unroll
        for (int d = 1; d < 16; d <<= 1) {
            int t = __shfl_up(s, d, 64);
            if (tid >= d) s += t;
        }
        int st = s - c;
        rs[tid] = st > 512 ? 512 : st;
        if (tid == 15) rs[16] = s > 512 ? 512 : s;
    }
    __syncthreads();
    for (int q = 0; q < ne; ++q) {
        int dl = ml[q] & 15;
        int p = rs[dl] + (ml[q] >> 4);
        if (p < 512) sorted[p] = (unsigned short)(ew[q] & 0xFFFFu);
    }
    __syncthreads();

    // per-node processing: 4 waves x 4 nodes each
    int lane = tid & 63, wv = tid >> 6;
    int g = lane >> 4, gl = lane & 15;
    const float4 att4 = *(const float4*)(att + gl * 4);
    // att . LeakyReLU(t) == sum c1*att_c*t + c2*att_c*|t|
    const float c1 = 0.5f * (1.f + NEG), c2 = 0.5f * (1.f - NEG);
    float4 a1 = make_float4(c1 * att4.x, c1 * att4.y, c1 * att4.z, c1 * att4.w);
    float4 a2 = make_float4(c2 * att4.x, c2 * att4.y, c2 * att4.z, c2 * att4.w);
    int nb = b * 64 + qq * 16;
    for (int t = 0; t < 4; ++t) {
        int nl = wv * 4 + t;
        int node = nb + nl;
        if (node >= nN) break;
        const float4 xr4 = *(const float4*)(xr + (size_t)node * HID + gl * 4);
        float4 acc = make_float4(0.f, 0.f, 0.f, 0.f);
        float denom = 0.f;
        // self loop: group 0 only
        if (g == 0) {
            ushort4 us = *(const ushort4*)(xlb + (size_t)node * HID + gl * 4);
            float xsx = bf2f(us.x), xsy = bf2f(us.y), xsz = bf2f(us.z), xsw = bf2f(us.w);
            float tx = xsx + xr4.x, ty = xsy + xr4.y;
            float tz = xsz + xr4.z, tw = xsw + xr4.w;
            float r = a1.x * tx;
            r = fmaf(a2.x, fabsf(tx), r);
            r = fmaf(a1.y, ty, r); r = fmaf(a2.y, fabsf(ty), r);
            r = fmaf(a1.z, tz, r); r = fmaf(a2.z, fabsf(tz), r);
            r = fmaf(a1.w, tw, r); r = fmaf(a2.w, fabsf(tw), r);
            r += __shfl_xor(r, 1, 64);
            r += __shfl_xor(r, 2, 64);
            r += __shfl_xor(r, 4, 64);
            r += __shfl_xor(r, 8, 64);
            float ev = __expf(r);
            denom = ev;
            acc.x = ev * xsx; acc.y = ev * xsy;
            acc.z = ev * xsz; acc.w = ev * xsw;
        }
        int s0 = rs[nl], s1 = rs[nl + 1];
        int last = s1 - 1;
        for (int base = s0; base < s1; base += 16) {
            int kb = base + g * 4;
            int k0 = (kb     <= last) ? kb     : last;
            int k1 = (kb + 1 <= last) ? kb + 1 : last;
            int k2 = (kb + 2 <= last) ? kb + 2 : last;
            int k3 = (kb + 3 <= last) ? kb + 3 : last;
            int j0 = sorted[k0], j1 = sorted[k1], j2 = sorted[k2], j3 = sorted[k3];
            ushort4 ua = *(const ushort4*)(xlb + (size_t)j0 * HID + gl * 4);
            ushort4 ub = *(const ushort4*)(xlb + (size_t)j1 * HID + gl * 4);
            ushort4 uc = *(const ushort4*)(xlb + (size_t)j2 * HID + gl * 4);
            ushort4 ud = *(const ushort4*)(xlb + (size_t)j3 * HID + gl * 4);
            float xax = bf2f(ua.x), xay = bf2f(ua.y), xaz = bf2f(ua.z), xaw = bf2f(ua.w);
            float xbx = bf2f(ub.x), xby = bf2f(ub.y), xbz = bf2f(ub.z), xbw = bf2f(ub.w);
            float xcx = bf2f(uc.x), xcy = bf2f(uc.y), xcz = bf2f(uc.z), xcw = bf2f(uc.w);
            float xdx = bf2f(ud.x), xdy = bf2f(ud.y), xdz = bf2f(ud.z), xdw = bf2f(ud.w);

            float t0, t1, t2, t3, ra, rb, rc, rd;
            t0 = xax + xr4.x; t1 = xay + xr4.y; t2 = xaz + xr4.z; t3 = xaw + xr4.w;
            ra = a1.x * t0;        ra = fmaf(a2.x, fabsf(t0), ra);
            ra = fmaf(a1.y, t1, ra); ra = fmaf(a2.y, fabsf(t1), ra);
            ra = fmaf(a1.z, t2, ra); ra = fmaf(a2.z, fabsf(t2), ra);
            ra = fmaf(a1.w, t3, ra); ra = fmaf(a2.w, fabsf(t3), ra);
            t0 = xbx + xr4.x; t1 = xby + xr4.y; t2 = xbz + xr4.z; t3 = xbw + xr4.w;
            rb = a1.x * t0;        rb = fmaf(a2.x, fabsf(t0), rb);
            rb = fmaf(a1.y, t1, rb); rb = fmaf(a2.y, fabsf(t1), rb);
            rb = fmaf(a1.z, t2, rb); rb = fmaf(a2.z, fabsf(t2), rb);
            rb = fmaf(a1.w, t3, rb); rb = fmaf(a2.w, fabsf(t3), rb);
            t0 = xcx + xr4.x; t1 = xcy + xr4.y; t2 = xcz + xr4.z; t3 = xcw + xr4.w;
            rc = a1.x * t0;        rc = fmaf(a2.x, fabsf(t0), rc);
            rc = fmaf(a1.y, t1, rc); rc = fmaf(a2.y, fabsf(t1), rc);
            rc = fmaf(a1.z, t2, rc); rc = fmaf(a2.z, fabsf(t2), rc);
            rc = fmaf(a1.w, t3, rc); rc = fmaf(a2.w, fabsf(t3), rc);
            t0 = xdx + xr4.x; t1 = xdy + xr4.y; t2 = xdz + xr4.z; t3 = xdw + xr4.w;
            rd = a1.x * t0;        rd = fmaf(a2.x, fabsf(t0), rd);
            rd = fmaf(a1.y, t1, rd); rd = fmaf(a2.y, fabsf(t1), rd);
            rd = fmaf(a1.z, t2, rd); rd = fmaf(a2.z, fabsf(t2), rd);
            rd = fmaf(a1.w, t3, rd); rd = fmaf(a2.w, fabsf(t3), rd);

            ra += __shfl_xor(ra, 1, 64); rb += __shfl_xor(rb, 1, 64);
            rc += __shfl_xor(rc, 1, 64); rd += __shfl_xor(rd, 1, 64);
            ra += __shfl_xor(ra, 2, 64); rb += __shfl_xor(rb, 2, 64);
            rc += __shfl_xor(rc, 2, 64); rd += __shfl_xor(rd, 2, 64);
            ra += __shfl_xor(ra, 4, 64); rb += __shfl_xor(rb, 4, 64);
            rc += __shfl_xor(rc, 4, 64); rd += __shfl_xor(rd, 4, 64);
            ra += __shfl_xor(ra, 8, 64); rb += __shfl_xor(rb, 8, 64);
            rc += __shfl_xor(rc, 8, 64); rd += __shfl_xor(rd, 8, 64);

            float ea = (kb     < s1) ? __expf(ra) : 0.f;
            float eb = (kb + 1 < s1) ? __expf(rb) : 0.f;
            float ec = (kb + 2 < s1) ? __expf(rc) : 0.f;
            float ed = (kb + 3 < s1) ? __expf(rd) : 0.f;
            denom += (ea + eb) + (ec + ed);
            acc.x = fmaf(ea, xax, acc.x); acc.x = fmaf(eb, xbx, acc.x);
            acc.x = fmaf(ec, xcx, acc.x); acc.x = fmaf(ed, xdx, acc.x);
            acc.y = fmaf(ea, xay, acc.y); acc.y = fmaf(eb, xby, acc.y);
            acc.y = fmaf(ec, xcy, acc.y); acc.y = fmaf(ed, xdy, acc.y);
            acc.z = fmaf(ea, xaz, acc.z); acc.z = fmaf(eb, xbz, acc.z);
            acc.z = fmaf(ec, xcz, acc.z); acc.z = fmaf(ed, xdz, acc.z);
            acc.w = fmaf(ea, xaw, acc.w); acc.w = fmaf(eb, xbw, acc.w);
            acc.w = fmaf(ec, xcw, acc.w); acc.w = fmaf(ed, xdw, acc.w);
        }
        denom += __shfl_xor(denom, 16, 64);
        denom += __shfl_xor(denom, 32, 64);
        acc.x += __shfl_xor(acc.x, 16, 64); acc.x += __shfl_xor(acc.x, 32, 64);
        acc.y += __shfl_xor(acc.y, 16, 64); acc.y += __shfl_xor(acc.y, 32, 64);
        acc.z += __shfl_xor(acc.z, 16, 64); acc.z += __shfl_xor(acc.z, 32, 64);
        acc.w += __shfl_xor(acc.w, 16, 64); acc.w += __shfl_xor(acc.w, 32, 64);
        float inv = 1.f / (denom + 1e-16f);
        float4 b4 = *(const float4*)(bias_conv + gl * 4);
        float hx = fmaf(acc.x, inv, b4.x);
        float hy = fmaf(acc.y, inv, b4.y);
        float hz = fmaf(acc.z, inv, b4.z);
        float hw = fmaf(acc.w, inv, b4.w);
        hx = (hx > 0.f) ? hx : (__expf(hx) - 1.f);
        hy = (hy > 0.f) ? hy : (__expf(hy) - 1.f);
        hz = (hz > 0.f) ? hz : (__expf(hz) - 1.f);
        hw = (hw > 0.f) ? hw : (__expf(hw) - 1.f);
        if (g == 0) {
            unsigned short hix = f2bf(hx), hiy = f2bf(hy),
                           hiz = f2bf(hz), hiw = f2bf(hw);
            ushort4 vhi = make_ushort4(hix, hiy, hiz, hiw);
            ushort4 vlo = make_ushort4(f2bf(hx - bf2f(hix)), f2bf(hy - bf2f(hiy)),
                                       f2bf(hz - bf2f(hiz)), f2bf(hw - bf2f(hiw)));
            *(ushort4*)(&Hhi[nl * 72 + gl * 4]) = vhi;
            *(ushort4*)(&Hlo[nl * 72 + gl * 4]) = vlo;
        }
    }
    __syncthreads();

    // ---- block-level epilogue GEMM: out[16x64] = H[16x64] @ W_lin^T --------
    bf16x8 Wh[2], Wl[2];
    #pragma unroll
    for (int s = 0; s < 2; ++s) {
        const float* wr = W_lin + (size_t)(wv * 16 + gl) * HID + s * 32 + g * 8;
        float4 w0 = *(const float4*)(wr);
        float4 w1 = *(const float4*)(wr + 4);
        float wf[8] = {w0.x, w0.y, w0.z, w0.w, w1.x, w1.y, w1.z, w1.w};
        #pragma unroll
        for (int j = 0; j < 8; ++j) {
            unsigned short h = f2bf(wf[j]);
            Wh[s][j] = (short)h;
            Wl[s][j] = (short)f2bf(wf[j] - bf2f(h));
        }
    }
    float blin = b_lin[wv * 16 + gl];
    {
        f32x4 d = {0.f, 0.f, 0.f, 0.f};
        int arow = gl * 72 + g * 8;
        #pragma unroll
        for (int s = 0; s < 2; ++s) {
            bf16x8 ah = *(const bf16x8*)(&Hhi[arow + s * 32]);
            bf16x8 al = *(const bf16x8*)(&Hlo[arow + s * 32]);
            d = __builtin_amdgcn_mfma_f32_16x16x32_bf16(ah, Wh[s], d, 0, 0, 0);
            d = __builtin_amdgcn_mfma_f32_16x16x32_bf16(ah, Wl[s], d, 0, 0, 0);
            d = __builtin_amdgcn_mfma_f32_16x16x32_bf16(al, Wh[s], d, 0, 0, 0);
        }
        #pragma unroll
        for (int r = 0; r < 4; ++r) {
            int node = nb + g * 4 + r;
            if (node < nN)
                out[(size_t)node * HID + wv * 16 + gl] = d[r] + blin;
        }
    }
}

extern "C" void kernel_launch(void* const* d_in, const int* in_sizes, int n_in,
                              void* d_out, int out_size, void* d_ws, size_t ws_size,
                              hipStream_t stream) {
    const float* x      = (const float*)d_in[0];
    const int*   ei     = (const int*)d_in[1];
    // d_in[2] = edge_weight: unused by the reference
    const float* W_l    = (const float*)d_in[3];
    const float* W_r    = (const float*)d_in[4];
    const float* att    = (const float*)d_in[5];
    const float* bias_c = (const float*)d_in[6];
    const float* W_lin  = (const float*)d_in[7];
    const float* b_lin  = (const float*)d_in[8];
    float* out = (float*)d_out;

    int N = in_sizes[0] / IN_CH;
    int E = in_sizes[2];
    const int* srcp = ei;
    const int* dstp = ei + E;
    int NB = (N + 63) / 64;   // buckets (<= 1024)

    char* ws = (char*)d_ws;
    float* xr = (float*)ws;                                         // N*64 f32
    unsigned short* xlb = (unsigned short*)(xr + (size_t)N * HID);  // N*64 bf16
    int* gcursor = (int*)(xlb + (size_t)N * HID);                   // 1024
    unsigned* pairs = (unsigned*)(gcursor + 1024);                  // NB*2048

    hipMemsetAsync(gcursor, 0, 1024 * sizeof(int), stream);
    proj_part<<<NB, 512, 0, stream>>>(x, W_l, W_r, xlb, xr, srcp, dstp,
                                      gcursor, pairs, N, E);
    gat_sorted<<<NB * 4, 256, 0, stream>>>(xlb, xr, pairs, gcursor,
                                           att, bias_c, W_lin, b_lin, out, N);
}

// Round 12
// 163.458 us; speedup vs baseline: 1.1523x; 1.0636x over previous
//
#include <hip/hip_runtime.h>

#define IN_CH 128
#define HID 64
#define NEG 0.2f

typedef short bf16x8 __attribute__((ext_vector_type(8)));
typedef float f32x4  __attribute__((ext_vector_type(4)));

__device__ __forceinline__ unsigned short f2bf(float f) {
    unsigned u = __float_as_uint(f);
    u += 0x7fffu + ((u >> 16) & 1u);   // RNE
    return (unsigned short)(u >> 16);
}
__device__ __forceinline__ float bf2f(unsigned short h) {
    return __uint_as_float((unsigned)h << 16);
}

// ------- K1: MFMA projections + concentrated quarter-bucket partition -------
// Phase A: unchanged (all blocks).
// Phase B: only the first NB/4 blocks participate, each with a 4x chunk
// (12 edges/thread, static-indexed stash). Restores R8's reservation cost
// (196 x 256 counter-lines = 50K line-touches, ~620K atomics) while
// producing the 4096-way layout that R9's gat (55.6us measured) consumes.
__global__ __launch_bounds__(512, 4) void proj_part(
    const float* __restrict__ x, const float* __restrict__ W_l,
    const float* __restrict__ W_r,
    unsigned short* __restrict__ xlb, float* __restrict__ xr,
    const int* __restrict__ src, const int* __restrict__ dst,
    int* __restrict__ gcursor, unsigned* __restrict__ pairs,
    int nN, int E)
{
    __shared__ unsigned short A_hi[64 * 136];   // 17.4 KB
    __shared__ unsigned short A_lo[64 * 136];   // 17.4 KB
    int tid = threadIdx.x;
    int nb = blockIdx.x * 64;
    int lane = tid & 63;
    int wid = __builtin_amdgcn_readfirstlane(tid >> 6);
    int mat = wid >> 2;
    int ct  = (wid & 3) * 16;
    int n = lane & 15, quad = lane >> 4;

    const float* __restrict__ W = mat ? W_r : W_l;
    bf16x8 Bh[4], Bl[4];
    #pragma unroll
    for (int s = 0; s < 4; ++s) {
        const float* wr = W + (size_t)(ct + n) * IN_CH + s * 32 + quad * 8;
        float4 w0 = *(const float4*)(wr);
        float4 w1 = *(const float4*)(wr + 4);
        float wf[8] = {w0.x, w0.y, w0.z, w0.w, w1.x, w1.y, w1.z, w1.w};
        #pragma unroll
        for (int j = 0; j < 8; ++j) {
            unsigned short h = f2bf(wf[j]);
            Bh[s][j] = (short)h;
            Bl[s][j] = (short)f2bf(wf[j] - bf2f(h));
        }
    }

    #pragma unroll
    for (int it = 0; it < 2; ++it) {
        int gi = it * 512 + tid;
        int row = gi >> 4, c8 = gi & 15;
        int node = nb + row;
        uint4 hi = make_uint4(0, 0, 0, 0), lo = make_uint4(0, 0, 0, 0);
        if (node < nN) {
            const float* xp = x + (size_t)node * IN_CH + c8 * 8;
            float4 f0 = *(const float4*)(xp);
            float4 f1 = *(const float4*)(xp + 4);
            float xf[8] = {f0.x, f0.y, f0.z, f0.w, f1.x, f1.y, f1.z, f1.w};
            unsigned hh[8], ll[8];
            #pragma unroll
            for (int j = 0; j < 8; ++j) {
                unsigned short h = f2bf(xf[j]);
                hh[j] = h;
                ll[j] = f2bf(xf[j] - bf2f(h));
            }
            hi = make_uint4(hh[0] | (hh[1] << 16), hh[2] | (hh[3] << 16),
                            hh[4] | (hh[5] << 16), hh[6] | (hh[7] << 16));
            lo = make_uint4(ll[0] | (ll[1] << 16), ll[2] | (ll[3] << 16),
                            ll[4] | (ll[5] << 16), ll[6] | (ll[7] << 16));
        }
        *(uint4*)(&A_hi[row * 136 + c8 * 8]) = hi;
        *(uint4*)(&A_lo[row * 136 + c8 * 8]) = lo;
    }
    __syncthreads();

    #pragma unroll
    for (int mt = 0; mt < 4; ++mt) {
        f32x4 d = {0.f, 0.f, 0.f, 0.f};
        int arow = (mt * 16 + n) * 136 + quad * 8;
        #pragma unroll
        for (int s = 0; s < 4; ++s) {
            bf16x8 ah = *(const bf16x8*)(&A_hi[arow + s * 32]);
            bf16x8 al = *(const bf16x8*)(&A_lo[arow + s * 32]);
            d = __builtin_amdgcn_mfma_f32_16x16x32_bf16(ah, Bh[s], d, 0, 0, 0);
            d = __builtin_amdgcn_mfma_f32_16x16x32_bf16(ah, Bl[s], d, 0, 0, 0);
            d = __builtin_amdgcn_mfma_f32_16x16x32_bf16(al, Bh[s], d, 0, 0, 0);
        }
        #pragma unroll
        for (int r = 0; r < 4; ++r) {
            int node = nb + mt * 16 + quad * 4 + r;
            if (node < nN) {
                if (mat)
                    xr[(size_t)node * HID + ct + n] = d[r];
                else
                    xlb[(size_t)node * HID + ct + n] = f2bf(d[r]);
            }
        }
    }

    // ------- Phase B: concentrated rank-stash append (first NB/4 blocks) ----
    __syncthreads();
    int PB = ((int)gridDim.x + 3) >> 2;
    if ((int)blockIdx.x < PB) {
        int* lh = (int*)A_hi;          // lhist[4096] (atomic returns rank)
        int* lb = (int*)A_lo;          // lbase[4096]
        for (int i = tid; i < 4096; i += 512) lh[i] = 0;
        __syncthreads();

        int C = ((E + PB - 1) / PB + 3) & ~3;    // chunk ~6124, mult of 4
        int lo = blockIdx.x * C;
        int hi = lo + C; if (hi > E) hi = E;

        // 12 edges/thread: pw = src | dlocal<<16 | bucket<<20 (bucket<=3124,
        // so marker 0xFFFFFFFF (bucket 4095) cannot collide). Static indexing.
        unsigned pw[12];
        unsigned rk[12];
        #pragma unroll
        for (int s = 0; s < 3; ++s) {
            int i0 = lo + s * 2048 + tid * 4;
            int4 s4, d4;
            bool full = (i0 + 3 < hi);
            if (full) {
                s4 = *(const int4*)(src + i0);
                d4 = *(const int4*)(dst + i0);
            }
            #pragma unroll
            for (int j = 0; j < 4; ++j) {
                int q = s * 4 + j;
                int e = i0 + j;
                int sv = 0, dv = 0;
                bool ok;
                if (full) {
                    sv = (&s4.x)[j]; dv = (&d4.x)[j]; ok = true;
                } else {
                    ok = (e < hi);
                    if (ok) { sv = src[e]; dv = dst[e]; }
                }
                if (ok) {
                    int b = dv >> 4;
                    pw[q] = (unsigned)sv | (((unsigned)dv & 15u) << 16)
                                         | ((unsigned)b << 20);
                    rk[q] = (unsigned)atomicAdd(&lh[b], 1);
                } else {
                    pw[q] = 0xFFFFFFFFu;
                    rk[q] = 0;
                }
            }
        }
        __syncthreads();
        for (int i = tid; i < 4096; i += 512) {
            int c = lh[i];
            lb[i] = c ? atomicAdd(&gcursor[i], c) : 0;
        }
        __syncthreads();
        #pragma unroll
        for (int q = 0; q < 12; ++q) {
            if (pw[q] != 0xFFFFFFFFu) {
                int b = (int)(pw[q] >> 20);
                int p = lb[b] + (int)rk[q];
                if (p < 512) pairs[(b << 9) + p] = pw[q] & 0xFFFFFu;
            }
        }
    }
}

// ------- K2: quarter-bucket sort + wave attention + MFMA epilogue -----------
// EXACT R9 form (measured 55.6us): block = one 16-node quarter-bucket
// (grid ~3125), direct partitioned read, rank-stash prologue, 4 waves x
// 4 nodes, 16x64 MFMA epilogue.
__global__ __launch_bounds__(256, 8) void gat_sorted(
    const unsigned short* __restrict__ xlb, const float* __restrict__ xr,
    const unsigned* __restrict__ pairs, const int* __restrict__ bcnt,
    const float* __restrict__ att, const float* __restrict__ bias_conv,
    const float* __restrict__ W_lin, const float* __restrict__ b_lin,
    float* __restrict__ out, int nN)
{
    __shared__ unsigned short sorted[512];    // 1 KB
    __shared__ unsigned short Hhi[16 * 72];   // 2.25 KB
    __shared__ unsigned short Hlo[16 * 72];   // 2.25 KB
    __shared__ int cnt[16];
    __shared__ int rs[17];
    int tid = threadIdx.x;
    if (tid < 16) cnt[tid] = 0;
    __syncthreads();

    int blk = blockIdx.x;          // quarter-bucket of 16 dst nodes
    int M = bcnt[blk];
    if (M > 512) M = 512;
    const unsigned* __restrict__ pb = pairs + ((size_t)blk << 9);

    // coalesced load; rank-stash (atomic returns within-bucket rank)
    unsigned ew[2];
    int dl[2], rk[2];
    int ne = 0;
    for (int i = tid; i < M; i += 256) {
        unsigned w = pb[i];
        ew[ne] = w;
        dl[ne] = (w >> 16) & 15;
        rk[ne] = atomicAdd(&cnt[dl[ne]], 1);
        ++ne;
    }
    __syncthreads();
    if (tid < 16) {
        int c = cnt[tid];
        int s = c;
        #pragma unroll
        for (int d = 1; d < 16; d <<= 1) {
            int t = __shfl_up(s, d, 64);
            if (tid >= d) s += t;
        }
        rs[tid] = s - c;
        if (tid == 15) rs[16] = s;
    }
    __syncthreads();
    for (int q = 0; q < ne; ++q)
        sorted[rs[dl[q]] + rk[q]] = (unsigned short)(ew[q] & 0xFFFFu);
    __syncthreads();

    // per-node processing: 4 waves x 4 nodes each
    int lane = tid & 63, wv = tid >> 6;
    int g = lane >> 4, gl = lane & 15;
    const float4 att4 = *(const float4*)(att + gl * 4);
    // att . LeakyReLU(t) == sum c1*att_c*t + c2*att_c*|t|
    const float c1 = 0.5f * (1.f + NEG), c2 = 0.5f * (1.f - NEG);
    float4 a1 = make_float4(c1 * att4.x, c1 * att4.y, c1 * att4.z, c1 * att4.w);
    float4 a2 = make_float4(c2 * att4.x, c2 * att4.y, c2 * att4.z, c2 * att4.w);
    int nb = blk * 16;
    for (int t = 0; t < 4; ++t) {
        int nl = wv * 4 + t;
        int node = nb + nl;
        if (node >= nN) break;
        const float4 xr4 = *(const float4*)(xr + (size_t)node * HID + gl * 4);
        float4 acc = make_float4(0.f, 0.f, 0.f, 0.f);
        float denom = 0.f;
        // self loop: group 0 only
        if (g == 0) {
            ushort4 us = *(const ushort4*)(xlb + (size_t)node * HID + gl * 4);
            float xsx = bf2f(us.x), xsy = bf2f(us.y), xsz = bf2f(us.z), xsw = bf2f(us.w);
            float tx = xsx + xr4.x, ty = xsy + xr4.y;
            float tz = xsz + xr4.z, tw = xsw + xr4.w;
            float r = a1.x * tx;
            r = fmaf(a2.x, fabsf(tx), r);
            r = fmaf(a1.y, ty, r); r = fmaf(a2.y, fabsf(ty), r);
            r = fmaf(a1.z, tz, r); r = fmaf(a2.z, fabsf(tz), r);
            r = fmaf(a1.w, tw, r); r = fmaf(a2.w, fabsf(tw), r);
            r += __shfl_xor(r, 1, 64);
            r += __shfl_xor(r, 2, 64);
            r += __shfl_xor(r, 4, 64);
            r += __shfl_xor(r, 8, 64);
            float ev = __expf(r);
            denom = ev;
            acc.x = ev * xsx; acc.y = ev * xsy;
            acc.z = ev * xsz; acc.w = ev * xsw;
        }
        int s0 = rs[nl], s1 = rs[nl + 1];
        int last = s1 - 1;
        for (int base = s0; base < s1; base += 16) {
            int kb = base + g * 4;
            int k0 = (kb     <= last) ? kb     : last;
            int k1 = (kb + 1 <= last) ? kb + 1 : last;
            int k2 = (kb + 2 <= last) ? kb + 2 : last;
            int k3 = (kb + 3 <= last) ? kb + 3 : last;
            int j0 = sorted[k0], j1 = sorted[k1], j2 = sorted[k2], j3 = sorted[k3];
            ushort4 ua = *(const ushort4*)(xlb + (size_t)j0 * HID + gl * 4);
            ushort4 ub = *(const ushort4*)(xlb + (size_t)j1 * HID + gl * 4);
            ushort4 uc = *(const ushort4*)(xlb + (size_t)j2 * HID + gl * 4);
            ushort4 ud = *(const ushort4*)(xlb + (size_t)j3 * HID + gl * 4);
            float xax = bf2f(ua.x), xay = bf2f(ua.y), xaz = bf2f(ua.z), xaw = bf2f(ua.w);
            float xbx = bf2f(ub.x), xby = bf2f(ub.y), xbz = bf2f(ub.z), xbw = bf2f(ub.w);
            float xcx = bf2f(uc.x), xcy = bf2f(uc.y), xcz = bf2f(uc.z), xcw = bf2f(uc.w);
            float xdx = bf2f(ud.x), xdy = bf2f(ud.y), xdz = bf2f(ud.z), xdw = bf2f(ud.w);

            float t0, t1, t2, t3, ra, rb, rc, rd;
            t0 = xax + xr4.x; t1 = xay + xr4.y; t2 = xaz + xr4.z; t3 = xaw + xr4.w;
            ra = a1.x * t0;        ra = fmaf(a2.x, fabsf(t0), ra);
            ra = fmaf(a1.y, t1, ra); ra = fmaf(a2.y, fabsf(t1), ra);
            ra = fmaf(a1.z, t2, ra); ra = fmaf(a2.z, fabsf(t2), ra);
            ra = fmaf(a1.w, t3, ra); ra = fmaf(a2.w, fabsf(t3), ra);
            t0 = xbx + xr4.x; t1 = xby + xr4.y; t2 = xbz + xr4.z; t3 = xbw + xr4.w;
            rb = a1.x * t0;        rb = fmaf(a2.x, fabsf(t0), rb);
            rb = fmaf(a1.y, t1, rb); rb = fmaf(a2.y, fabsf(t1), rb);
            rb = fmaf(a1.z, t2, rb); rb = fmaf(a2.z, fabsf(t2), rb);
            rb = fmaf(a1.w, t3, rb); rb = fmaf(a2.w, fabsf(t3), rb);
            t0 = xcx + xr4.x; t1 = xcy + xr4.y; t2 = xcz + xr4.z; t3 = xcw + xr4.w;
            rc = a1.x * t0;        rc = fmaf(a2.x, fabsf(t0), rc);
            rc = fmaf(a1.y, t1, rc); rc = fmaf(a2.y, fabsf(t1), rc);
            rc = fmaf(a1.z, t2, rc); rc = fmaf(a2.z, fabsf(t2), rc);
            rc = fmaf(a1.w, t3, rc); rc = fmaf(a2.w, fabsf(t3), rc);
            t0 = xdx + xr4.x; t1 = xdy + xr4.y; t2 = xdz + xr4.z; t3 = xdw + xr4.w;
            rd = a1.x * t0;        rd = fmaf(a2.x, fabsf(t0), rd);
            rd = fmaf(a1.y, t1, rd); rd = fmaf(a2.y, fabsf(t1), rd);
            rd = fmaf(a1.z, t2, rd); rd = fmaf(a2.z, fabsf(t2), rd);
            rd = fmaf(a1.w, t3, rd); rd = fmaf(a2.w, fabsf(t3), rd);

            ra += __shfl_xor(ra, 1, 64); rb += __shfl_xor(rb, 1, 64);
            rc += __shfl_xor(rc, 1, 64); rd += __shfl_xor(rd, 1, 64);
            ra += __shfl_xor(ra, 2, 64); rb += __shfl_xor(rb, 2, 64);
            rc += __shfl_xor(rc, 2, 64); rd += __shfl_xor(rd, 2, 64);
            ra += __shfl_xor(ra, 4, 64); rb += __shfl_xor(rb, 4, 64);
            rc += __shfl_xor(rc, 4, 64); rd += __shfl_xor(rd, 4, 64);
            ra += __shfl_xor(ra, 8, 64); rb += __shfl_xor(rb, 8, 64);
            rc += __shfl_xor(rc, 8, 64); rd += __shfl_xor(rd, 8, 64);

            float ea = (kb     < s1) ? __expf(ra) : 0.f;
            float eb = (kb + 1 < s1) ? __expf(rb) : 0.f;
            float ec = (kb + 2 < s1) ? __expf(rc) : 0.f;
            float ed = (kb + 3 < s1) ? __expf(rd) : 0.f;
            denom += (ea + eb) + (ec + ed);
            acc.x = fmaf(ea, xax, acc.x); acc.x = fmaf(eb, xbx, acc.x);
            acc.x = fmaf(ec, xcx, acc.x); acc.x = fmaf(ed, xdx, acc.x);
            acc.y = fmaf(ea, xay, acc.y); acc.y = fmaf(eb, xby, acc.y);
            acc.y = fmaf(ec, xcy, acc.y); acc.y = fmaf(ed, xdy, acc.y);
            acc.z = fmaf(ea, xaz, acc.z); acc.z = fmaf(eb, xbz, acc.z);
            acc.z = fmaf(ec, xcz, acc.z); acc.z = fmaf(ed, xdz, acc.z);
            acc.w = fmaf(ea, xaw, acc.w); acc.w = fmaf(eb, xbw, acc.w);
            acc.w = fmaf(ec, xcw, acc.w); acc.w = fmaf(ed, xdw, acc.w);
        }
        denom += __shfl_xor(denom, 16, 64);
        denom += __shfl_xor(denom, 32, 64);
        acc.x += __shfl_xor(acc.x, 16, 64); acc.x += __shfl_xor(acc.x, 32, 64);
        acc.y += __shfl_xor(acc.y, 16, 64); acc.y += __shfl_xor(acc.y, 32, 64);
        acc.z += __shfl_xor(acc.z, 16, 64); acc.z += __shfl_xor(acc.z, 32, 64);
        acc.w += __shfl_xor(acc.w, 16, 64); acc.w += __shfl_xor(acc.w, 32, 64);
        float inv = 1.f / (denom + 1e-16f);
        float4 b4 = *(const float4*)(bias_conv + gl * 4);
        float hx = fmaf(acc.x, inv, b4.x);
        float hy = fmaf(acc.y, inv, b4.y);
        float hz = fmaf(acc.z, inv, b4.z);
        float hw = fmaf(acc.w, inv, b4.w);
        hx = (hx > 0.f) ? hx : (__expf(hx) - 1.f);
        hy = (hy > 0.f) ? hy : (__expf(hy) - 1.f);
        hz = (hz > 0.f) ? hz : (__expf(hz) - 1.f);
        hw = (hw > 0.f) ? hw : (__expf(hw) - 1.f);
        if (g == 0) {
            unsigned short hix = f2bf(hx), hiy = f2bf(hy),
                           hiz = f2bf(hz), hiw = f2bf(hw);
            ushort4 vhi = make_ushort4(hix, hiy, hiz, hiw);
            ushort4 vlo = make_ushort4(f2bf(hx - bf2f(hix)), f2bf(hy - bf2f(hiy)),
                                       f2bf(hz - bf2f(hiz)), f2bf(hw - bf2f(hiw)));
            *(ushort4*)(&Hhi[nl * 72 + gl * 4]) = vhi;
            *(ushort4*)(&Hlo[nl * 72 + gl * 4]) = vlo;
        }
    }
    __syncthreads();

    // ---- block-level epilogue GEMM: out[16x64] = H[16x64] @ W_lin^T --------
    bf16x8 Wh[2], Wl[2];
    #pragma unroll
    for (int s = 0; s < 2; ++s) {
        const float* wr = W_lin + (size_t)(wv * 16 + gl) * HID + s * 32 + g * 8;
        float4 w0 = *(const float4*)(wr);
        float4 w1 = *(const float4*)(wr + 4);
        float wf[8] = {w0.x, w0.y, w0.z, w0.w, w1.x, w1.y, w1.z, w1.w};
        #pragma unroll
        for (int j = 0; j < 8; ++j) {
            unsigned short h = f2bf(wf[j]);
            Wh[s][j] = (short)h;
            Wl[s][j] = (short)f2bf(wf[j] - bf2f(h));
        }
    }
    float blin = b_lin[wv * 16 + gl];
    {
        f32x4 d = {0.f, 0.f, 0.f, 0.f};
        int arow = gl * 72 + g * 8;
        #pragma unroll
        for (int s = 0; s < 2; ++s) {
            bf16x8 ah = *(const bf16x8*)(&Hhi[arow + s * 32]);
            bf16x8 al = *(const bf16x8*)(&Hlo[arow + s * 32]);
            d = __builtin_amdgcn_mfma_f32_16x16x32_bf16(ah, Wh[s], d, 0, 0, 0);
            d = __builtin_amdgcn_mfma_f32_16x16x32_bf16(ah, Wl[s], d, 0, 0, 0);
            d = __builtin_amdgcn_mfma_f32_16x16x32_bf16(al, Wh[s], d, 0, 0, 0);
        }
        #pragma unroll
        for (int r = 0; r < 4; ++r) {
            int node = nb + g * 4 + r;
            if (node < nN)
                out[(size_t)node * HID + wv * 16 + gl] = d[r] + blin;
        }
    }
}

extern "C" void kernel_launch(void* const* d_in, const int* in_sizes, int n_in,
                              void* d_out, int out_size, void* d_ws, size_t ws_size,
                              hipStream_t stream) {
    const float* x      = (const float*)d_in[0];
    const int*   ei     = (const int*)d_in[1];
    // d_in[2] = edge_weight: unused by the reference
    const float* W_l    = (const float*)d_in[3];
    const float* W_r    = (const float*)d_in[4];
    const float* att    = (const float*)d_in[5];
    const float* bias_c = (const float*)d_in[6];
    const float* W_lin  = (const float*)d_in[7];
    const float* b_lin  = (const float*)d_in[8];
    float* out = (float*)d_out;

    int N = in_sizes[0] / IN_CH;
    int E = in_sizes[2];
    const int* srcp = ei;
    const int* dstp = ei + E;
    int NB = (N + 63) / 64;   // proj blocks
    int NQ = (N + 15) / 16;   // quarter-buckets (<= 4096)

    char* ws = (char*)d_ws;
    float* xr = (float*)ws;                                         // N*64 f32
    unsigned short* xlb = (unsigned short*)(xr + (size_t)N * HID);  // N*64 bf16
    int* gcursor = (int*)(xlb + (size_t)N * HID);                   // 4096
    unsigned* pairs = (unsigned*)(gcursor + 4096);                  // NQ*512

    hipMemsetAsync(gcursor, 0, 4096 * sizeof(int), stream);
    proj_part<<<NB, 512, 0, stream>>>(x, W_l, W_r, xlb, xr, srcp, dstp,
                                      gcursor, pairs, N, E);
    gat_sorted<<<NQ, 256, 0, stream>>>(xlb, xr, pairs, gcursor,
                                       att, bias_c, W_lin, b_lin, out, N);
}